// Round 9
// baseline (666.760 us; speedup 1.0000x reference)
//
#include <hip/hip_runtime.h>
#include <math.h>

#define NN   100000
#define NE   1600000
#define FIN  256
#define HID  64
#define NC   40
#define NBKT 391          // buckets of 256 nodes: bucket = dst >> 8
#define EPB  6250         // edges per phase-A block (256 * 6250 = NE exactly)
#define CAP  4608         // per-bucket capacity (mean 4092, sd 64 -> 8 sigma slack)
#define KPW  13           // nodes per wave in persistent gathers (8192 waves)

typedef __attribute__((ext_vector_type(8))) short short8;
typedef __attribute__((ext_vector_type(4))) float float4v;

static __device__ __forceinline__ short f2bf(float f) {   // RNE f32 -> bf16 bits
    unsigned u = __float_as_uint(f);
    u += 0x7FFFu + ((u >> 16) & 1u);
    return (short)(u >> 16);
}
static __device__ __forceinline__ float bf2f(unsigned short b) {
    return __uint_as_float((unsigned)b << 16);
}

// ---------- W1 -> bf16, transposed to [n][k] ----------
__global__ __launch_bounds__(256) void w1cvt_k(const float* __restrict__ W1,
                                               short* __restrict__ w1t) {
    int t = blockIdx.x * 256 + threadIdx.x;   // 16384
    int k = t >> 6, n = t & 63;
    w1t[n * FIN + k] = f2bf(W1[k * HID + n]);
}

// ---------- phase A: partition edges into 391 coarse buckets ----------
__global__ __launch_bounds__(256) void phaseA_k(const int* __restrict__ src,
                                                const int* __restrict__ dst,
                                                const float* __restrict__ w,
                                                int* __restrict__ cursor,      // [NBKT*16]
                                                int2* __restrict__ bucketbuf) {
    __shared__ int  hist[NBKT];
    __shared__ int  sc[512];
    __shared__ int  loc_base[NBKT];
    __shared__ int  loc_cur[NBKT];
    __shared__ int  gb[NBKT];
    __shared__ int2 buf[EPB];          // 50 KB
    const int t  = threadIdx.x;
    const int e0 = blockIdx.x * EPB;

    for (int i = t; i < NBKT; i += 256) hist[i] = 0;
    __syncthreads();
    for (int i = t; i < EPB; i += 256) atomicAdd(&hist[dst[e0 + i] >> 8], 1);
    __syncthreads();
    sc[t]       = (t       < NBKT) ? hist[t]       : 0;
    sc[t + 256] = (t + 256 < NBKT) ? hist[t + 256] : 0;
    __syncthreads();
    for (int off = 1; off < 512; off <<= 1) {
        int a0 = (t >= off) ? sc[t - off] : 0;
        int a1 = sc[t + 256 - off];
        __syncthreads();
        sc[t] += a0; sc[t + 256] += a1;
        __syncthreads();
    }
    for (int i = t; i < NBKT; i += 256) {
        int base = sc[i] - hist[i];
        loc_base[i] = base;
        loc_cur[i]  = base;
        gb[i] = atomicAdd(&cursor[i * 16], hist[i]);
    }
    __syncthreads();
    for (int i = t; i < EPB; i += 256) {
        int e = e0 + i;
        int d = dst[e];
        int b = d >> 8;
        int p = atomicAdd(&loc_cur[b], 1);
        buf[p] = make_int2(src[e] | ((d & 255) << 17), __float_as_int(w[e]));
    }
    __syncthreads();
    for (int b = t; b < NBKT; b += 256) {
        int lb = loc_base[b], n = hist[b];
        int2* dstp = bucketbuf + (size_t)b * CAP + gb[b];
        for (int i = 0; i < n; ++i) dstp[i] = buf[lb + i];
    }
}

// ---------- scan of bucket counts -> bucket bases ----------
__global__ __launch_bounds__(512) void scanB_k(const int* __restrict__ cursor,
                                               int* __restrict__ bucketbase,
                                               int* __restrict__ row_start) {
    __shared__ int tmp[512];
    int t = threadIdx.x;
    int v = (t < NBKT) ? cursor[t * 16] : 0;
    tmp[t] = v;
    __syncthreads();
    for (int off = 1; off < 512; off <<= 1) {
        int add = (t >= off) ? tmp[t - off] : 0;
        __syncthreads(); tmp[t] += add; __syncthreads();
    }
    if (t < NBKT) bucketbase[t] = tmp[t] - v;
    if (t == 0) { bucketbase[NBKT] = NE; row_start[NN] = NE; }
}

// ---------- phase B: per-bucket CSR build, rows octant-sorted by src; row_start, dinv, qoff ----------
__global__ __launch_bounds__(256) void phaseB_k(const int* __restrict__ bucketbase,
                                                const int2* __restrict__ bucketbuf,
                                                int2* __restrict__ e8,
                                                int* __restrict__ row_start,
                                                float* __restrict__ dinv,
                                                uint2* __restrict__ qoff) {
    __shared__ int2 buf2[CAP];          // 36.9 KB
    __shared__ int  hist2[2048];        // 8 KB   key = (dstlow<<3) | (src>>14)
    __shared__ int  cur2[2048];         // 8 KB
    __shared__ int  tmp[256];
    const int b = blockIdx.x, t = threadIdx.x;
    const int g0   = bucketbase[b];
    const int cntb = bucketbase[b + 1] - g0;
    const int n0   = b * 256;
    const int nnb  = (NN - n0 < 256) ? (NN - n0) : 256;

    for (int i = t; i < 2048; i += 256) hist2[i] = 0;
    __syncthreads();
    const int2* bb = bucketbuf + (size_t)b * CAP;
    for (int i = t; i < cntb; i += 256) {
        int kx = bb[i].x;
        atomicAdd(&hist2[((kx >> 17) << 3) | ((kx & 0x1FFFF) >> 14)], 1);
    }
    __syncthreads();
    int hq[8];
    int nodesum = 0;
#pragma unroll
    for (int q = 0; q < 8; ++q) { hq[q] = hist2[8 * t + q]; nodesum += hq[q]; }
    tmp[t] = nodesum;
    __syncthreads();
    for (int off = 1; off < 256; off <<= 1) {
        int add = (t >= off) ? tmp[t - off] : 0;
        __syncthreads(); tmp[t] += add; __syncthreads();
    }
    const int nb = tmp[t] - nodesum;      // node base within bucket (exclusive)
    {
        unsigned lo = 0, hi = 0; int run = 0;
#pragma unroll
        for (int q = 0; q < 8; ++q) {
            cur2[8 * t + q] = nb + run;
            run += hq[q];
            unsigned by = (unsigned)run & 255u;   // cum count through octant q (rowlen <= 255)
            if (q < 4) lo |= by << (8 * q); else hi |= by << (8 * (q - 4));
        }
        if (t < nnb) { row_start[n0 + t] = g0 + nb; qoff[n0 + t] = make_uint2(lo, hi); }
    }
    __syncthreads();
    for (int i = t; i < cntb; i += 256) {
        int2 kv = bb[i];
        int key = ((kv.x >> 17) << 3) | ((kv.x & 0x1FFFF) >> 14);
        int p = atomicAdd(&cur2[key], 1);
        buf2[p] = make_int2(kv.x & 0x1FFFF, kv.y);
    }
    __syncthreads();
    for (int i = t; i < cntb; i += 256) e8[g0 + i] = buf2[i];
    if (t < nnb) {
        float s = 0.f;
        for (int j = nb; j < nb + nodesum; ++j) s += __int_as_float(buf2[j].y);
        dinv[n0 + t] = rsqrtf(1.0f + s);
    }
}

// ---------- layer-1 GEMM via MFMA bf16, pre-scaled: h1'[r] = bf16(dinv[r] * (x@W1)[r]) ----------
__global__ __launch_bounds__(256) void gemm1_mfma_k(const float* __restrict__ x,
                                                    const short* __restrict__ w1t,  // bf16 [64][256]
                                                    const float* __restrict__ dinv,
                                                    unsigned short* __restrict__ h1) {
    const int wave = threadIdx.x >> 6;
    const int lane = threadIdx.x & 63;
    const int m    = lane & 15;
    const int quad = lane >> 4;
    const int r0   = blockIdx.x * 64 + wave * 16;
    const int row  = r0 + m;
    const int rcl  = (row < NN) ? row : (NN - 1);
    const float* xrow = x + (size_t)rcl * FIN + quad * 8;

    float4v acc0 = {0.f,0.f,0.f,0.f}, acc1 = acc0, acc2 = acc0, acc3 = acc0;

#pragma unroll
    for (int kc = 0; kc < 8; ++kc) {
        const int kof = kc * 32 + quad * 8;
        float4 xa = *(const float4*)(xrow + kc * 32);
        float4 xb = *(const float4*)(xrow + kc * 32 + 4);
        short8 a;
        a[0] = f2bf(xa.x); a[1] = f2bf(xa.y); a[2] = f2bf(xa.z); a[3] = f2bf(xa.w);
        a[4] = f2bf(xb.x); a[5] = f2bf(xb.y); a[6] = f2bf(xb.z); a[7] = f2bf(xb.w);
        short8 b0 = *(const short8*)(w1t + (0 * 16 + m) * FIN + kof);
        short8 b1 = *(const short8*)(w1t + (1 * 16 + m) * FIN + kof);
        short8 b2 = *(const short8*)(w1t + (2 * 16 + m) * FIN + kof);
        short8 b3 = *(const short8*)(w1t + (3 * 16 + m) * FIN + kof);
        acc0 = __builtin_amdgcn_mfma_f32_16x16x32_bf16(a, b0, acc0, 0, 0, 0);
        acc1 = __builtin_amdgcn_mfma_f32_16x16x32_bf16(a, b1, acc1, 0, 0, 0);
        acc2 = __builtin_amdgcn_mfma_f32_16x16x32_bf16(a, b2, acc2, 0, 0, 0);
        acc3 = __builtin_amdgcn_mfma_f32_16x16x32_bf16(a, b3, acc3, 0, 0, 0);
    }
    // C/D layout: col = lane&15, row = quad*4 + reg
#pragma unroll
    for (int r = 0; r < 4; ++r) {
        int rr = r0 + quad * 4 + r;
        if (rr < NN) {
            float dv = dinv[rr];
            unsigned short* hp = h1 + (size_t)rr * HID + m;
            hp[0]  = (unsigned short)f2bf(acc0[r] * dv);
            hp[16] = (unsigned short)f2bf(acc1[r] * dv);
            hp[32] = (unsigned short)f2bf(acc2[r] * dv);
            hp[48] = (unsigned short)f2bf(acc3[r] * dv);
        }
    }
}

static __device__ __forceinline__ int qbyte(uint2 qo, int q) {   // cum count through octant q
    unsigned w = (q < 4) ? qo.x : qo.y;
    return (int)((w >> (8 * (q & 3))) & 255u);
}

// ---------- persistent gatherA: phase-aligned over src octants; emits R' = bf16(dv*relu(agg1+b1)) ----------
__global__ __launch_bounds__(256, 8) void gatherA_p(const int* __restrict__ row_start,
                                                    const uint2* __restrict__ qoff,
                                                    const int2* __restrict__ e8,
                                                    const float* __restrict__ dinv,
                                                    const unsigned short* __restrict__ h,
                                                    const float* __restrict__ b1,
                                                    unsigned short* __restrict__ Rp) {
    const int wid  = blockIdx.x * 4 + (threadIdx.x >> 6);   // 0..8191
    const int lane = threadIdx.x & 63;
    const int base = wid * KPW;
    float acc[KPW];
#pragma unroll
    for (int j = 0; j < KPW; ++j) acc[j] = 0.f;

    for (int q = 0; q < 7; ++q) {            // src octants, all waves in lockstep-ish
#pragma unroll
        for (int j = 0; j < KPW; ++j) {
            const int v = base + j;
            if (v < NN) {
                uint2 qo = qoff[v];
                int e_end = qbyte(qo, q);
                int e_beg = q ? qbyte(qo, q - 1) : 0;
                int rs = row_start[v];
                float a0 = 0.f;
                for (int i = rs + e_beg; i < rs + e_end; ++i) {
                    int2 a = e8[i];
                    a0 = fmaf(bf2f(h[(size_t)a.x * HID + lane]), __int_as_float(a.y), a0);
                }
                acc[j] += a0;
            }
        }
    }
#pragma unroll
    for (int j = 0; j < KPW; ++j) {
        const int v = base + j;
        if (v < NN) {
            const float dv = dinv[v];
            float r = dv * (acc[j] + bf2f(h[(size_t)v * HID + lane]));
            r = fmaxf(r + b1[lane], 0.f);
            Rp[(size_t)v * HID + lane] = (unsigned short)f2bf(dv * r);
        }
    }
}

// ---------- persistent gatherB: agg2 = dv*(sum w*R'[s]) + dv*R'[v] ----------
__global__ __launch_bounds__(256, 8) void gatherB_p(const int* __restrict__ row_start,
                                                    const uint2* __restrict__ qoff,
                                                    const int2* __restrict__ e8,
                                                    const float* __restrict__ dinv,
                                                    const unsigned short* __restrict__ Rp,
                                                    float* __restrict__ agg2) {
    const int wid  = blockIdx.x * 4 + (threadIdx.x >> 6);
    const int lane = threadIdx.x & 63;
    const int base = wid * KPW;
    float acc[KPW];
#pragma unroll
    for (int j = 0; j < KPW; ++j) acc[j] = 0.f;

    for (int q = 0; q < 7; ++q) {
#pragma unroll
        for (int j = 0; j < KPW; ++j) {
            const int v = base + j;
            if (v < NN) {
                uint2 qo = qoff[v];
                int e_end = qbyte(qo, q);
                int e_beg = q ? qbyte(qo, q - 1) : 0;
                int rs = row_start[v];
                float a0 = 0.f;
                for (int i = rs + e_beg; i < rs + e_end; ++i) {
                    int2 a = e8[i];
                    a0 = fmaf(bf2f(Rp[(size_t)a.x * HID + lane]), __int_as_float(a.y), a0);
                }
                acc[j] += a0;
            }
        }
    }
#pragma unroll
    for (int j = 0; j < KPW; ++j) {
        const int v = base + j;
        if (v < NN) {
            const float dv = dinv[v];
            agg2[(size_t)v * HID + lane] = dv * (acc[j] + bf2f(Rp[(size_t)v * HID + lane]));
        }
    }
}

// ---------- gemm3 + log_softmax: out = logsm(agg2 @ W2 + b2), thread per node ----------
__global__ __launch_bounds__(256) void gemm3_logsm_k(const float* __restrict__ agg2,
                                                     const float* __restrict__ W2,
                                                     const float* __restrict__ b2,
                                                     float* __restrict__ out) {
    __shared__ float w2s[HID * NC];
    __shared__ float b2s[NC];
    for (int i = threadIdx.x; i < HID * NC; i += 256) w2s[i] = W2[i];
    if (threadIdx.x < NC) b2s[threadIdx.x] = b2[threadIdx.x];
    __syncthreads();

    const int r = blockIdx.x * 256 + threadIdx.x;
    if (r >= NN) return;
    float acc[NC];
#pragma unroll
    for (int c = 0; c < NC; ++c) acc[c] = b2s[c];

    const float4* row4 = (const float4*)(agg2 + (size_t)r * HID);
    for (int kk = 0; kk < HID; kk += 4) {
        float4 v = row4[kk >> 2];
#pragma unroll
        for (int c = 0; c < NC; ++c) {
            acc[c] = fmaf(v.x, w2s[(kk + 0) * NC + c], acc[c]);
            acc[c] = fmaf(v.y, w2s[(kk + 1) * NC + c], acc[c]);
            acc[c] = fmaf(v.z, w2s[(kk + 2) * NC + c], acc[c]);
            acc[c] = fmaf(v.w, w2s[(kk + 3) * NC + c], acc[c]);
        }
    }
    float m = acc[0];
#pragma unroll
    for (int c = 1; c < NC; ++c) m = fmaxf(m, acc[c]);
    float s = 0.f;
#pragma unroll
    for (int c = 0; c < NC; ++c) s += __expf(acc[c] - m);
    float lg = m + __logf(s);
    float* outp = out + (size_t)r * NC;
#pragma unroll
    for (int c = 0; c < NC; c += 4)
        *(float4*)&outp[c] = make_float4(acc[c] - lg, acc[c+1] - lg, acc[c+2] - lg, acc[c+3] - lg);
}

extern "C" void kernel_launch(void* const* d_in, const int* in_sizes, int n_in,
                              void* d_out, int out_size, void* d_ws, size_t ws_size,
                              hipStream_t stream) {
    const float* x  = (const float*)d_in[0];
    const int*   ei = (const int*)d_in[1];     // [2, E]: row0=src, row1=dst
    const float* ea = (const float*)d_in[2];
    const float* W1 = (const float*)d_in[3];
    const float* b1 = (const float*)d_in[4];
    const float* W2 = (const float*)d_in[5];
    const float* b2 = (const float*)d_in[6];
    const int* src = ei;
    const int* dst = ei + NE;
    float* out = (float*)d_out;

    char* ws = (char*)d_ws;
    float* dinv       = (float*)(ws + 0);            //    400,000 B
    int*   row_start  = (int*)  (ws + 400000);       //    400,016 B (NN+1)
    int*   cursor     = (int*)  (ws + 800016);       //     25,024 B (391*16, line-padded)
    int*   bucketbase = (int*)  (ws + 825040);       //      1,568 B
    int2*  e8         = (int2*) (ws + 826608);       // 12,800,000 B
    unsigned short* h1 = (unsigned short*)(ws + 13626608);   // 12,800,000 B (bf16, dinv-prescaled)
    unsigned short* Rp = (unsigned short*)(ws + 26426608);   // 12,800,000 B (bf16, dinv-prescaled)
    float* agg2       = (float*)(ws + 39226608);     // 25,600,000 B
    short* w1t        = (short*)(ws + 64826608);     //     32,768 B
    uint2* qoff       = (uint2*)(ws + 64859376);     //    800,000 B -> total 65.66 MB
    int2*  bucketbuf  = (int2*)agg2;                 // 14.4 MB, aliases agg2 (dead until gatherB)

    hipMemsetAsync(cursor, 0, 391 * 16 * sizeof(int), stream);

    w1cvt_k <<<64,   256, 0, stream>>>(W1, w1t);
    phaseA_k<<<256,  256, 0, stream>>>(src, dst, ea, cursor, bucketbuf);
    scanB_k <<<1,    512, 0, stream>>>(cursor, bucketbase, row_start);
    phaseB_k<<<NBKT, 256, 0, stream>>>(bucketbase, bucketbuf, e8, row_start, dinv, qoff);

    gemm1_mfma_k <<<(NN + 63) / 64, 256, 0, stream>>>(x, w1t, dinv, h1);
    gatherA_p    <<<2048, 256, 0, stream>>>(row_start, qoff, e8, dinv, h1, b1, Rp);
    gatherB_p    <<<2048, 256, 0, stream>>>(row_start, qoff, e8, dinv, Rp, agg2);
    gemm3_logsm_k<<<(NN + 255) / 256, 256, 0, stream>>>(agg2, W2, b2, out);
}